// Round 1
// baseline (603.840 us; speedup 1.0000x reference)
//
#include <hip/hip_runtime.h>
#include <stdint.h>

// Fused MHA: out = softmax_causal((xq Wq^T)(xk Wk^T)^T / 8) (xv Wv^T) Wo^T
// B=4 S=2048 E=1024 H=16 D=64.
// Workspace layout (requires >= 104 MB):
//   [0,16)   qb  (bf16 cast of query)  -- reused as AO (attn output) after Q-proj
//   [16,32)  kb, [32,48) vb
//   [48,50) Wqb [50,52) Wkb [52,54) Wvb [54,56) Wob
//   [56,72)  Qp  [72,88) Kp  [88,104) Vt (per-head transposed V: [b,h,d,s])

#define LOG2E 1.44269504088896340736f

typedef __bf16 bf16;
typedef __attribute__((ext_vector_type(8))) __bf16 bf16x8;
typedef __attribute__((ext_vector_type(4))) __bf16 bf16x4;
typedef __attribute__((ext_vector_type(4))) float f32x4;

static constexpr int Bq = 4, Sq = 2048, Eq = 1024, Hq = 16, Dq = 64;
static constexpr int Mq = Bq * Sq; // 8192 tokens

__device__ __forceinline__ f32x4 mfma16(bf16x8 a, bf16x8 b, f32x4 c) {
  return __builtin_amdgcn_mfma_f32_16x16x32_bf16(a, b, c, 0, 0, 0);
}

// ---------------- cast fp32 -> bf16, 8 elems/thread ----------------
__global__ void cast_f32_to_bf16(const float* __restrict__ in,
                                 bf16* __restrict__ out, int n8) {
  int i = blockIdx.x * blockDim.x + threadIdx.x;
  if (i >= n8) return;
  const float4* p = (const float4*)in;
  float4 a = p[i * 2], b = p[i * 2 + 1];
  bf16x8 v;
  v[0] = (bf16)a.x; v[1] = (bf16)a.y; v[2] = (bf16)a.z; v[3] = (bf16)a.w;
  v[4] = (bf16)b.x; v[5] = (bf16)b.y; v[6] = (bf16)b.z; v[7] = (bf16)b.w;
  ((bf16x8*)out)[i] = v;
}

// ---------------- GEMM: C[M,N] = A[M,K] * W[N,K]^T  (bf16 in, M=8192 N=K=1024)
// MODE 0: C bf16 row-major.  MODE 1: V-transposed store Vt[(b*16+h)*64+d][s].
// MODE 2: C f32 row-major (final output).
// 128x128 tile, BK=64, 4 waves, each wave owns 64x64 (4x4 of 16x16 frags).
// LDS XOR-swizzled (T2): read/write byte ^= (row&7)<<4 to kill the 16-way
// bank conflict of 128B-stride ds_read_b128.
template <int MODE>
__global__ __launch_bounds__(256) void gemm_bt(const bf16* __restrict__ A,
                                               const bf16* __restrict__ W,
                                               void* __restrict__ Cout) {
  __shared__ __align__(16) bf16 Alds[128 * 64];
  __shared__ __align__(16) bf16 Blds[128 * 64];

  int bid = blockIdx.x;
  int nwg = gridDim.x;                      // 512, divisible by 8
  int wg = (bid & 7) * (nwg >> 3) + (bid >> 3); // XCD swizzle (bijective)
  int tm = wg >> 3, tn = wg & 7;            // 64 x 8 tiles
  int tid = threadIdx.x;
  int l = tid & 63, wv = tid >> 6;
  int wm = wv >> 1, wn = wv & 1;
  int l15 = l & 15, lg = l >> 4;

  f32x4 acc[4][4] = {};
  const size_t arow = (size_t)tm * 128, brow = (size_t)tn * 128;

  for (int k0 = 0; k0 < 1024; k0 += 64) {
    // ---- stage 128x64 A and B tiles (reg-staged, swizzled LDS write) ----
#pragma unroll
    for (int j = 0; j < 4; ++j) {
      int loc = tid * 16 + j * 4096;        // linear byte offset in tile
      int r = loc >> 7;                     // row (128B rows)
      int c = (loc & 127) >> 1;             // k element within row
      bf16x8 va = *(const bf16x8*)(A + (arow + r) * 1024 + k0 + c);
      bf16x8 vb = *(const bf16x8*)(W + (brow + r) * 1024 + k0 + c);
      int swz = loc ^ ((r & 7) << 4);
      *(bf16x8*)((char*)Alds + swz) = va;
      *(bf16x8*)((char*)Blds + swz) = vb;
    }
    __syncthreads();
    // ---- compute: 2 k-chunks of 32, 16 frag-pairs, 32 MFMAs ----
#pragma unroll
    for (int kk = 0; kk < 2; ++kk) {
      bf16x8 af[4], bfr[4];
#pragma unroll
      for (int t = 0; t < 4; ++t) {
        int ma = wm * 64 + t * 16 + l15;
        int offa = (ma * 128 + 16 * lg + 64 * kk) ^ ((ma & 7) << 4);
        af[t] = *(const bf16x8*)((const char*)Alds + offa);
        int nb = wn * 64 + t * 16 + l15;
        int offb = (nb * 128 + 16 * lg + 64 * kk) ^ ((nb & 7) << 4);
        bfr[t] = *(const bf16x8*)((const char*)Blds + offb);
      }
#pragma unroll
      for (int mt = 0; mt < 4; ++mt)
#pragma unroll
        for (int nt = 0; nt < 4; ++nt)
          acc[mt][nt] = mfma16(af[mt], bfr[nt], acc[mt][nt]);
    }
    __syncthreads();
  }

  // ---- epilogue ----
  int mbase = tm * 128 + wm * 64;
  int nbase = tn * 128 + wn * 64;
  if (MODE == 0 || MODE == 2) {
#pragma unroll
    for (int mt = 0; mt < 4; ++mt) {
#pragma unroll
      for (int nt = 0; nt < 4; ++nt) {
        int m0 = mbase + mt * 16 + (lg << 2);
        int n = nbase + nt * 16 + l15;
#pragma unroll
        for (int rg = 0; rg < 4; ++rg) {
          if (MODE == 0)
            ((bf16*)Cout)[(size_t)(m0 + rg) * 1024 + n] = (bf16)acc[mt][nt][rg];
          else
            ((float*)Cout)[(size_t)(m0 + rg) * 1024 + n] = acc[mt][nt][rg];
        }
      }
    }
  } else { // MODE 1: Vt[(b*16+h)*64 + d][s], b=m>>11, s=m&2047, h=n>>6, d=n&63
#pragma unroll
    for (int mt = 0; mt < 4; ++mt) {
#pragma unroll
      for (int nt = 0; nt < 4; ++nt) {
        int m0 = mbase + mt * 16 + (lg << 2);
        int n = nbase + nt * 16 + l15;
        bf16x4 vv;
#pragma unroll
        for (int rg = 0; rg < 4; ++rg) vv[rg] = (bf16)acc[mt][nt][rg];
        int bb = m0 >> 11, s0 = m0 & 2047;
        size_t off = ((size_t)((bb * 16 + (n >> 6)) * 64 + (n & 63))) * 2048 + s0;
        *(bf16x4*)((bf16*)Cout + off) = vv;
      }
    }
  }
}

// ---------------- causal flash attention ----------------
// 1 wave = 16 q-rows of one (b,h). KVBLK=32. Swapped QK^T (mfma(K,Q)) puts
// P in registers with q=lane&15, k=4*(lane>>4)+reg+16*tile, which is a valid
// B-operand enumeration for the PV mfma (A = Vt loaded with the same one).
__global__ __launch_bounds__(256) void attn_kernel(const bf16* __restrict__ Qp,
                                                   const bf16* __restrict__ Kp,
                                                   const bf16* __restrict__ Vt,
                                                   bf16* __restrict__ AO) {
  int bid = blockIdx.x;
  bid = (bid & 7) * (gridDim.x >> 3) + (bid >> 3);  // XCD swizzle (2048%8==0)
  int w = bid * 4 + (threadIdx.x >> 6);
  int l = threadIdx.x & 63;
  int qt = w & 127, bh = w >> 7;
  int b = bh >> 4, h = bh & 15;
  int q0 = qt * 16;
  int l15 = l & 15, lg = l >> 4;
  int q_g = q0 + l15;
  const float sc = 0.125f * LOG2E;  // fold 1/sqrt(D) and log2(e)

  // Q fragments: d = 8*lg + i (+32 for second chunk), 16B contiguous loads
  const bf16* qbase = Qp + (size_t)(b * Sq + q0 + l15) * Eq + h * Dq + 8 * lg;
  bf16x8 qf0 = *(const bf16x8*)qbase;
  bf16x8 qf1 = *(const bf16x8*)(qbase + 32);

  float m2 = -1e30f, r = 0.f;
  f32x4 oacc[4] = {};
  const bf16* vrow = Vt + (size_t)(bh * 64 + l15) * Sq + 4 * lg;
  const bf16* krow = Kp + (size_t)(b * Sq + l15) * Eq + h * Dq + 8 * lg;

  int nkc = (q0 + 16 + 31) >> 5;  // chunks of 32 kv rows, causal bound
  for (int kc = 0; kc < nkc; ++kc) {
    int k0 = kc << 5;
    // QK^T: scores^T[k][q], two 16-row k tiles
    f32x4 s01[2];
#pragma unroll
    for (int kt = 0; kt < 2; ++kt) {
      const bf16* kb = krow + (size_t)(k0 + kt * 16) * Eq;
      bf16x8 kf0 = *(const bf16x8*)kb;
      bf16x8 kf1 = *(const bf16x8*)(kb + 32);
      f32x4 z = {0.f, 0.f, 0.f, 0.f};
      f32x4 t = mfma16(kf0, qf0, z);
      s01[kt] = mfma16(kf1, qf1, t);
    }
    // scale (+ causal mask only on diagonal-crossing chunks)
    float p[2][4];
    float cmax = -1e30f;
    bool needmask = (k0 + 31 > q0);
#pragma unroll
    for (int kt = 0; kt < 2; ++kt)
#pragma unroll
      for (int rg = 0; rg < 4; ++rg) {
        float v = s01[kt][rg] * sc;
        if (needmask) {
          int k_g = k0 + kt * 16 + 4 * lg + rg;
          v = (k_g <= q_g) ? v : -1e30f;
        }
        p[kt][rg] = v;
        cmax = fmaxf(cmax, v);
      }
    cmax = fmaxf(cmax, __shfl_xor(cmax, 16));
    cmax = fmaxf(cmax, __shfl_xor(cmax, 32));
    float newm = fmaxf(m2, cmax);
    float corr = exp2f(m2 - newm);
    m2 = newm;
    r *= corr;
#pragma unroll
    for (int dt = 0; dt < 4; ++dt) oacc[dt] *= corr;
    bf16x8 pf;
#pragma unroll
    for (int kt = 0; kt < 2; ++kt)
#pragma unroll
      for (int rg = 0; rg < 4; ++rg) {
        float e = exp2f(p[kt][rg] - m2);
        r += e;
        pf[kt * 4 + rg] = (bf16)e;
      }
    // PV: out^T[d][q] += Vt[d][k] * P[q][k]
#pragma unroll
    for (int dt = 0; dt < 4; ++dt) {
      const bf16* vb = vrow + (size_t)(dt * 16) * Sq + k0;
      bf16x4 vlo = *(const bf16x4*)vb;
      bf16x4 vhi = *(const bf16x4*)(vb + 16);
      bf16x8 vf;
#pragma unroll
      for (int i = 0; i < 4; ++i) { vf[i] = vlo[i]; vf[4 + i] = vhi[i]; }
      oacc[dt] = mfma16(vf, pf, oacc[dt]);
    }
  }
  // epilogue: sum r across the 4 lane-groups sharing q, normalize, store
  r += __shfl_xor(r, 16);
  r += __shfl_xor(r, 32);
  float inv = 1.0f / r;
  bf16* obase = AO + (size_t)(b * Sq + q0 + l15) * Eq + h * Dq;
#pragma unroll
  for (int dt = 0; dt < 4; ++dt) {
    bf16x4 vv;
#pragma unroll
    for (int rg = 0; rg < 4; ++rg) vv[rg] = (bf16)(oacc[dt][rg] * inv);
    *(bf16x4*)(obase + dt * 16 + 4 * lg) = vv;
  }
}

extern "C" void kernel_launch(void* const* d_in, const int* in_sizes, int n_in,
                              void* d_out, int out_size, void* d_ws, size_t ws_size,
                              hipStream_t stream) {
  (void)in_sizes; (void)n_in; (void)out_size; (void)ws_size;
  const float* dq = (const float*)d_in[0];
  const float* dk = (const float*)d_in[1];
  const float* dv = (const float*)d_in[2];
  const float* wq = (const float*)d_in[3];
  const float* wk = (const float*)d_in[4];
  const float* wv = (const float*)d_in[5];
  const float* wo = (const float*)d_in[6];
  // d_in[7] = causal mask (tril) -- structure known, not read.

  char* ws = (char*)d_ws;
  const size_t MB = 1u << 20;
  bf16* qb  = (bf16*)(ws + 0 * MB);
  bf16* kb  = (bf16*)(ws + 16 * MB);
  bf16* vb  = (bf16*)(ws + 32 * MB);
  bf16* wqb = (bf16*)(ws + 48 * MB);
  bf16* wkb = (bf16*)(ws + 50 * MB);
  bf16* wvb = (bf16*)(ws + 52 * MB);
  bf16* wob = (bf16*)(ws + 54 * MB);
  bf16* Qp  = (bf16*)(ws + 56 * MB);
  bf16* Kp  = (bf16*)(ws + 72 * MB);
  bf16* Vt  = (bf16*)(ws + 88 * MB);
  bf16* AO  = qb;  // alias: qb is dead after the Q projection

  int n8 = Mq * Eq / 8;  // 1,048,576 threads -> 4096 blocks
  int w8 = Eq * Eq / 8;  // 131,072 -> 512 blocks
  cast_f32_to_bf16<<<n8 / 256, 256, 0, stream>>>(dq, qb, n8);
  cast_f32_to_bf16<<<n8 / 256, 256, 0, stream>>>(dk, kb, n8);
  cast_f32_to_bf16<<<n8 / 256, 256, 0, stream>>>(dv, vb, n8);
  cast_f32_to_bf16<<<w8 / 256, 256, 0, stream>>>(wq, wqb, w8);
  cast_f32_to_bf16<<<w8 / 256, 256, 0, stream>>>(wk, wkb, w8);
  cast_f32_to_bf16<<<w8 / 256, 256, 0, stream>>>(wv, wvb, w8);
  cast_f32_to_bf16<<<w8 / 256, 256, 0, stream>>>(wo, wob, w8);

  gemm_bt<0><<<512, 256, 0, stream>>>(qb, wqb, (void*)Qp);
  gemm_bt<0><<<512, 256, 0, stream>>>(kb, wkb, (void*)Kp);
  gemm_bt<1><<<512, 256, 0, stream>>>(vb, wvb, (void*)Vt);
  attn_kernel<<<2048, 256, 0, stream>>>(Qp, Kp, Vt, AO);
  gemm_bt<2><<<512, 256, 0, stream>>>(AO, wob, d_out);
}

// Round 2
// 332.294 us; speedup vs baseline: 1.8172x; 1.8172x over previous
//
#include <hip/hip_runtime.h>
#include <stdint.h>

// Fused MHA: out = softmax_causal((xq Wq^T)(xk Wk^T)^T / 8) (xv Wv^T) Wo^T
// B=4 S=2048 E=1024 H=16 D=64.
// Workspace layout (requires >= 104 MB):
//   [0,16)   qb (bf16 query)  -- reused as AO after Q-proj
//   [16,32)  kb, [32,48) vb
//   [48,50) Wqb [50,52) Wkb [52,54) Wvb [54,56) Wob
//   [56,72)  Qp  [72,88) Kp  [88,104) Vt (per-head transposed V: [b,h,d,s])

#define LOG2E 1.44269504088896340736f

typedef __bf16 bf16;
typedef __attribute__((ext_vector_type(8))) __bf16 bf16x8;
typedef __attribute__((ext_vector_type(4))) __bf16 bf16x4;
typedef __attribute__((ext_vector_type(4))) float f32x4;

static constexpr int Bq = 4, Sq = 2048, Eq = 1024;
static constexpr int Mq = Bq * Sq; // 8192 tokens

__device__ __forceinline__ f32x4 mfma16(bf16x8 a, bf16x8 b, f32x4 c) {
  return __builtin_amdgcn_mfma_f32_16x16x32_bf16(a, b, c, 0, 0, 0);
}

__device__ __forceinline__ void gload16(const bf16* g, bf16* l) {
  __builtin_amdgcn_global_load_lds(
      (const __attribute__((address_space(1))) void*)g,
      (__attribute__((address_space(3))) void*)l, 16, 0, 0);
}

__device__ __forceinline__ bf16x8 vcat(bf16x4 lo, bf16x4 hi) {
  return __builtin_shufflevector(lo, hi, 0, 1, 2, 3, 4, 5, 6, 7);
}

__device__ __forceinline__ bf16x8 scale8(bf16x8 v, float s) {
  bf16x8 o;
#pragma unroll
  for (int i = 0; i < 8; ++i) o[i] = (bf16)((float)v[i] * s);
  return o;
}

__device__ __forceinline__ void store4(bf16* p, f32x4 a, float s) {
  bf16x4 v;
#pragma unroll
  for (int rg = 0; rg < 4; ++rg) v[rg] = (bf16)(a[rg] * s);
  *(bf16x4*)p = v;
}

// ---------------- cast fp32 -> bf16, 8 elems/thread ----------------
__global__ void cast_f32_to_bf16(const float* __restrict__ in,
                                 bf16* __restrict__ out, int n8) {
  int i = blockIdx.x * blockDim.x + threadIdx.x;
  if (i >= n8) return;
  const float4* p = (const float4*)in;
  float4 a = p[i * 2], b = p[i * 2 + 1];
  bf16x8 v;
  v[0] = (bf16)a.x; v[1] = (bf16)a.y; v[2] = (bf16)a.z; v[3] = (bf16)a.w;
  v[4] = (bf16)b.x; v[5] = (bf16)b.y; v[6] = (bf16)b.z; v[7] = (bf16)b.w;
  ((bf16x8*)out)[i] = v;
}

// ---------------- GEMM: C[M,N] = A[M,K] * W[N,K]^T  (M=8192 N=K=1024) ------
// m97 pattern: global_load_lds width-16 staging, linear LDS, 128x128 tile,
// BK=64, 4 waves, each wave 64x64 (4x4 of 16x16 frags).
// MODE 0: C bf16.  MODE 1: Vt[(b*16+h)*64+d][s] bf16.  MODE 2: C f32.
template <int MODE>
__global__ __launch_bounds__(256) void gemm_bt(const bf16* __restrict__ A,
                                               const bf16* __restrict__ W,
                                               void* __restrict__ Cout) {
  __shared__ __align__(16) bf16 Alds[128 * 64];
  __shared__ __align__(16) bf16 Blds[128 * 64];

  int bid = blockIdx.x;
  int nwg = gridDim.x;                          // 512, divisible by 8
  int wg = (bid & 7) * (nwg >> 3) + (bid >> 3); // XCD swizzle (bijective)
  int tm = wg >> 3, tn = wg & 7;                // 64 x 8 tiles
  int tid = threadIdx.x;
  int l = tid & 63, wv = tid >> 6;
  int wm = wv >> 1, wn = wv & 1;
  int l15 = l & 15, lg = l >> 4;

  f32x4 acc[4][4] = {};
  const size_t arow = (size_t)tm * 128, brow = (size_t)tn * 128;

  for (int k0 = 0; k0 < 1024; k0 += 64) {
#pragma unroll
    for (int j = 0; j < 4; ++j) {
      int loc = tid * 16 + j * 4096;  // linear byte offset in 16KB tile
      int r = loc >> 7;               // row (128B per row)
      int c = (loc & 127) >> 1;       // k element within row
      gload16(A + (arow + r) * 1024 + k0 + c, (bf16*)((char*)Alds + loc));
      gload16(W + (brow + r) * 1024 + k0 + c, (bf16*)((char*)Blds + loc));
    }
    __syncthreads();
#pragma unroll
    for (int kk = 0; kk < 2; ++kk) {
      bf16x8 af[4], bfr[4];
#pragma unroll
      for (int t = 0; t < 4; ++t) {
        int ma = wm * 64 + t * 16 + l15;
        af[t] = *(const bf16x8*)((const char*)Alds + ma * 128 + 16 * lg + 64 * kk);
        int nb = wn * 64 + t * 16 + l15;
        bfr[t] = *(const bf16x8*)((const char*)Blds + nb * 128 + 16 * lg + 64 * kk);
      }
#pragma unroll
      for (int mt = 0; mt < 4; ++mt)
#pragma unroll
        for (int nt = 0; nt < 4; ++nt)
          acc[mt][nt] = mfma16(af[mt], bfr[nt], acc[mt][nt]);
    }
    __syncthreads();
  }

  int mbase = tm * 128 + wm * 64;
  int nbase = tn * 128 + wn * 64;
  if (MODE == 0 || MODE == 2) {
#pragma unroll
    for (int mt = 0; mt < 4; ++mt) {
#pragma unroll
      for (int nt = 0; nt < 4; ++nt) {
        int m0 = mbase + mt * 16 + (lg << 2);
        int n = nbase + nt * 16 + l15;
#pragma unroll
        for (int rg = 0; rg < 4; ++rg) {
          if (MODE == 0)
            ((bf16*)Cout)[(size_t)(m0 + rg) * 1024 + n] = (bf16)acc[mt][nt][rg];
          else
            ((float*)Cout)[(size_t)(m0 + rg) * 1024 + n] = acc[mt][nt][rg];
        }
      }
    }
  } else { // MODE 1: Vt[(b*16+h)*64 + d][s]
#pragma unroll
    for (int mt = 0; mt < 4; ++mt) {
#pragma unroll
      for (int nt = 0; nt < 4; ++nt) {
        int m0 = mbase + mt * 16 + (lg << 2);
        int n = nbase + nt * 16 + l15;
        bf16x4 vv;
#pragma unroll
        for (int rg = 0; rg < 4; ++rg) vv[rg] = (bf16)acc[mt][nt][rg];
        int bb = m0 >> 11, s0 = m0 & 2047;
        size_t off = ((size_t)((bb * 16 + (n >> 6)) * 64 + (n & 63))) * 2048 + s0;
        *(bf16x4*)((bf16*)Cout + off) = vv;
      }
    }
  }
}

// ---------------- causal flash attention ----------------
// Wave = (bh, j); processes q-tiles t=j and t=63-j (32 rows each) -> uniform
// 65 chunks/wave. KVBLK=32, 2 q-frags share K/V frags. Swapped QK^T
// (mfma(K,Q)): P lands with q=lane&15, k=4*lg+reg(+16/tile) which is a valid
// B-operand enumeration for PV when Vt is loaded with the same one.
// Register ping-pong prefetch of next chunk's K/V. Row-sum via mfma(ones,P).
struct KVbuf {
  bf16x8 k00, k01, k10, k11;
  bf16x4 v0l, v0h, v1l, v1h, v2l, v2h, v3l, v3h;
};

#define LOADKV(BUF, kcv)                                                  \
  do {                                                                    \
    const bf16* _kr = krow + ((size_t)((kcv) << 5)) * 1024;               \
    BUF.k00 = *(const bf16x8*)_kr;                                        \
    BUF.k01 = *(const bf16x8*)(_kr + 32);                                 \
    BUF.k10 = *(const bf16x8*)(_kr + 16384);                              \
    BUF.k11 = *(const bf16x8*)(_kr + 16384 + 32);                         \
    const bf16* _vr = vrow + ((kcv) << 5);                                \
    BUF.v0l = *(const bf16x4*)_vr;                                        \
    BUF.v0h = *(const bf16x4*)(_vr + 16);                                 \
    BUF.v1l = *(const bf16x4*)(_vr + 32768);                              \
    BUF.v1h = *(const bf16x4*)(_vr + 32768 + 16);                         \
    BUF.v2l = *(const bf16x4*)(_vr + 65536);                              \
    BUF.v2h = *(const bf16x4*)(_vr + 65536 + 16);                         \
    BUF.v3l = *(const bf16x4*)(_vr + 98304);                              \
    BUF.v3h = *(const bf16x4*)(_vr + 98304 + 16);                         \
  } while (0)

#define CHUNK(BUF, kcv)                                                       \
  do {                                                                        \
    const int _k0 = (kcv) << 5;                                               \
    f32x4 _z = {0.f, 0.f, 0.f, 0.f};                                          \
    f32x4 s00 = mfma16(BUF.k01, q01, mfma16(BUF.k00, q00, _z));               \
    f32x4 s01v = mfma16(BUF.k11, q01, mfma16(BUF.k10, q00, _z));              \
    f32x4 s10 = mfma16(BUF.k01, q11, mfma16(BUF.k00, q10, _z));               \
    f32x4 s11v = mfma16(BUF.k11, q11, mfma16(BUF.k10, q10, _z));              \
    if ((kcv) == t) {                                                         \
      _Pragma("unroll") for (int rg = 0; rg < 4; ++rg) {                      \
        int kg = _k0 + 4 * lg + rg;                                           \
        if (kg > qg0) s00[rg] = -1e30f;                                       \
        if (kg + 16 > qg0) s01v[rg] = -1e30f;                                 \
        if (kg > qg1) s10[rg] = -1e30f;                                       \
        if (kg + 16 > qg1) s11v[rg] = -1e30f;                                 \
      }                                                                       \
    }                                                                         \
    float c0 = fmaxf(fmaxf(fmaxf(s00[0], s00[1]), fmaxf(s00[2], s00[3])),     \
                     fmaxf(fmaxf(s01v[0], s01v[1]), fmaxf(s01v[2], s01v[3])));\
    float c1 = fmaxf(fmaxf(fmaxf(s10[0], s10[1]), fmaxf(s10[2], s10[3])),     \
                     fmaxf(fmaxf(s11v[0], s11v[1]), fmaxf(s11v[2], s11v[3])));\
    c0 = fmaxf(c0, __shfl_xor(c0, 16));                                       \
    c0 = fmaxf(c0, __shfl_xor(c0, 32));                                       \
    c1 = fmaxf(c1, __shfl_xor(c1, 16));                                       \
    c1 = fmaxf(c1, __shfl_xor(c1, 32));                                       \
    if (!__all(c0 <= m0)) {                                                   \
      float _nm = fmaxf(m0, c0);                                              \
      float _cr = exp2f(m0 - _nm);                                            \
      m0 = _nm;                                                               \
      o00 *= _cr; o01 *= _cr; o02 *= _cr; o03 *= _cr; r0 *= _cr;              \
    }                                                                         \
    if (!__all(c1 <= m1)) {                                                   \
      float _nm = fmaxf(m1, c1);                                              \
      float _cr = exp2f(m1 - _nm);                                            \
      m1 = _nm;                                                               \
      o10 *= _cr; o11 *= _cr; o12 *= _cr; o13 *= _cr; r1 *= _cr;              \
    }                                                                         \
    bf16x8 p0, p1;                                                            \
    _Pragma("unroll") for (int rg = 0; rg < 4; ++rg) {                        \
      p0[rg] = (bf16)exp2f(s00[rg] - m0);                                     \
      p0[rg + 4] = (bf16)exp2f(s01v[rg] - m0);                                \
      p1[rg] = (bf16)exp2f(s10[rg] - m1);                                     \
      p1[rg + 4] = (bf16)exp2f(s11v[rg] - m1);                                \
    }                                                                         \
    r0 = mfma16(ones, p0, r0);                                                \
    r1 = mfma16(ones, p1, r1);                                                \
    {                                                                         \
      bf16x8 vf = vcat(BUF.v0l, BUF.v0h);                                     \
      o00 = mfma16(vf, p0, o00); o10 = mfma16(vf, p1, o10);                   \
    }                                                                         \
    {                                                                         \
      bf16x8 vf = vcat(BUF.v1l, BUF.v1h);                                     \
      o01 = mfma16(vf, p0, o01); o11 = mfma16(vf, p1, o11);                   \
    }                                                                         \
    {                                                                         \
      bf16x8 vf = vcat(BUF.v2l, BUF.v2h);                                     \
      o02 = mfma16(vf, p0, o02); o12 = mfma16(vf, p1, o12);                   \
    }                                                                         \
    {                                                                         \
      bf16x8 vf = vcat(BUF.v3l, BUF.v3h);                                     \
      o03 = mfma16(vf, p0, o03); o13 = mfma16(vf, p1, o13);                   \
    }                                                                         \
  } while (0)

__global__ __launch_bounds__(256) void attn_kernel(const bf16* __restrict__ Qp,
                                                   const bf16* __restrict__ Kp,
                                                   const bf16* __restrict__ Vt,
                                                   bf16* __restrict__ AO) {
  int bid = blockIdx.x;               // 512 blocks
  int x = bid & 7, rr = bid >> 3;     // x = XCD slot
  int bh = x * 8 + (rr & 7);          // 8 heads per XCD -> K/V L2-resident
  int j = (rr >> 3) * 4 + (threadIdx.x >> 6);  // 0..31
  int l = threadIdx.x & 63;
  int b = bh >> 4, h = bh & 15;
  int l15 = l & 15, lg = l >> 4;
  const float sc = 0.125f * LOG2E;
  bf16 one1 = (bf16)1.0f;
  bf16x8 ones = {one1, one1, one1, one1, one1, one1, one1, one1};

  const bf16* krow = Kp + ((size_t)(b * 2048 + l15)) * 1024 + h * 64 + 8 * lg;
  const bf16* vrow = Vt + ((size_t)(bh * 64 + l15)) * 2048 + 4 * lg;

#pragma unroll 1
  for (int pass = 0; pass < 2; ++pass) {
    int t = pass ? 63 - j : j;
    int q0 = t << 5;
    int qg0 = q0 + l15, qg1 = q0 + 16 + l15;
    const bf16* qb_ =
        Qp + ((size_t)(b * 2048 + q0 + l15)) * 1024 + h * 64 + 8 * lg;
    bf16x8 q00 = scale8(*(const bf16x8*)qb_, sc);
    bf16x8 q01 = scale8(*(const bf16x8*)(qb_ + 32), sc);
    bf16x8 q10 = scale8(*(const bf16x8*)(qb_ + 16384), sc);
    bf16x8 q11 = scale8(*(const bf16x8*)(qb_ + 16384 + 32), sc);

    float m0 = -1e30f, m1 = -1e30f;
    f32x4 r0 = {0.f, 0.f, 0.f, 0.f}, r1 = {0.f, 0.f, 0.f, 0.f};
    f32x4 o00 = {0.f, 0.f, 0.f, 0.f}, o01 = o00, o02 = o00, o03 = o00;
    f32x4 o10 = o00, o11 = o00, o12 = o00, o13 = o00;

    KVbuf bA, bB;
    int nkc = t + 1;
    LOADKV(bA, 0);
    int kc = 0;
    while (1) {
      if (kc + 1 < nkc) LOADKV(bB, kc + 1);
      CHUNK(bA, kc);
      if (++kc >= nkc) break;
      if (kc + 1 < nkc) LOADKV(bA, kc + 1);
      CHUNK(bB, kc);
      if (++kc >= nkc) break;
    }

    float inv0 = 1.0f / r0[0], inv1 = 1.0f / r1[0];
    bf16* ob = AO + ((size_t)(b * 2048 + q0 + l15)) * 1024 + h * 64 + 4 * lg;
    store4(ob + 0, o00, inv0);
    store4(ob + 16, o01, inv0);
    store4(ob + 32, o02, inv0);
    store4(ob + 48, o03, inv0);
    bf16* ob1 = ob + 16384;
    store4(ob1 + 0, o10, inv1);
    store4(ob1 + 16, o11, inv1);
    store4(ob1 + 32, o12, inv1);
    store4(ob1 + 48, o13, inv1);
  }
}

extern "C" void kernel_launch(void* const* d_in, const int* in_sizes, int n_in,
                              void* d_out, int out_size, void* d_ws, size_t ws_size,
                              hipStream_t stream) {
  (void)in_sizes; (void)n_in; (void)out_size; (void)ws_size;
  const float* dq = (const float*)d_in[0];
  const float* dk = (const float*)d_in[1];
  const float* dv = (const float*)d_in[2];
  const float* wq = (const float*)d_in[3];
  const float* wk = (const float*)d_in[4];
  const float* wv = (const float*)d_in[5];
  const float* wo = (const float*)d_in[6];

  char* ws = (char*)d_ws;
  const size_t MB = 1u << 20;
  bf16* qb  = (bf16*)(ws + 0 * MB);
  bf16* kb  = (bf16*)(ws + 16 * MB);
  bf16* vb  = (bf16*)(ws + 32 * MB);
  bf16* wqb = (bf16*)(ws + 48 * MB);
  bf16* wkb = (bf16*)(ws + 50 * MB);
  bf16* wvb = (bf16*)(ws + 52 * MB);
  bf16* wob = (bf16*)(ws + 54 * MB);
  bf16* Qp  = (bf16*)(ws + 56 * MB);
  bf16* Kp  = (bf16*)(ws + 72 * MB);
  bf16* Vt  = (bf16*)(ws + 88 * MB);
  bf16* AO  = qb;  // qb dead after Q projection

  int n8 = Mq * Eq / 8;
  int w8 = Eq * Eq / 8;
  cast_f32_to_bf16<<<n8 / 256, 256, 0, stream>>>(dq, qb, n8);
  cast_f32_to_bf16<<<n8 / 256, 256, 0, stream>>>(dk, kb, n8);
  cast_f32_to_bf16<<<n8 / 256, 256, 0, stream>>>(dv, vb, n8);
  cast_f32_to_bf16<<<w8 / 256, 256, 0, stream>>>(wq, wqb, w8);
  cast_f32_to_bf16<<<w8 / 256, 256, 0, stream>>>(wk, wkb, w8);
  cast_f32_to_bf16<<<w8 / 256, 256, 0, stream>>>(wv, wvb, w8);
  cast_f32_to_bf16<<<w8 / 256, 256, 0, stream>>>(wo, wob, w8);

  gemm_bt<0><<<512, 256, 0, stream>>>(qb, wqb, (void*)Qp);
  gemm_bt<0><<<512, 256, 0, stream>>>(kb, wkb, (void*)Kp);
  gemm_bt<1><<<512, 256, 0, stream>>>(vb, wvb, (void*)Vt);
  attn_kernel<<<512, 256, 0, stream>>>(Qp, Kp, Vt, AO);
  gemm_bt<2><<<512, 256, 0, stream>>>(AO, wob, d_out);
}